// Round 9
// baseline (250.747 us; speedup 1.0000x reference)
//
#include <hip/hip_runtime.h>
#include <hip/hip_bf16.h>

#define B_  2
#define T_  2048
#define NH_ 16
#define HS_ 64
#define C_  1024
#define SCL_ 128              // EMA chunk length
#define SCN_ (T_ / SCL_)      // 16 chunks
#define NT_  (T_ / 64)        // 32 key/query tiles
#define TEL_ 4096             // elements per 64x64 tile

typedef __attribute__((ext_vector_type(8))) short bf16x8;
typedef __attribute__((ext_vector_type(4))) float f32x4;

__device__ inline int pack_bf16(float a, float b) {
  union { __hip_bfloat16 h; unsigned short u; } ua, ub;
  ua.h = __float2bfloat16(a);
  ub.h = __float2bfloat16(b);
  return (int)(((unsigned)ub.u << 16) | (unsigned)ua.u);
}

// async global->LDS 16B: global ptr is PER-LANE; LDS dest must equal
// wave-uniform base + lane*16. Callers pass per-lane g AND l = base+lane*16.
__device__ inline void gl_lds16(const __hip_bfloat16* g, __hip_bfloat16* l) {
  __builtin_amdgcn_global_load_lds(
      (const __attribute__((address_space(1))) unsigned int*)g,
      (__attribute__((address_space(3))) unsigned int*)l, 16, 0, 0);
}

// ---------------------------------------------------------------------------
// fp32 -> bf16 elementwise (8 elems/thread)
// ---------------------------------------------------------------------------
__global__ __launch_bounds__(256) void cvt_bf16_kernel(const float* __restrict__ in,
                                                       __hip_bfloat16* __restrict__ out) {
  const int i = (blockIdx.x * 256 + threadIdx.x) * 8;
  const float4 a = *reinterpret_cast<const float4*>(in + i);
  const float4 b = *reinterpret_cast<const float4*>(in + i + 4);
  union { int s[4]; int4 v; } u;
  u.s[0] = pack_bf16(a.x, a.y);
  u.s[1] = pack_bf16(a.z, a.w);
  u.s[2] = pack_bf16(b.x, b.y);
  u.s[3] = pack_bf16(b.z, b.w);
  *reinterpret_cast<int4*>(out + i) = u.v;
}

// ---------------------------------------------------------------------------
// All 3 weights (fp32 K x N) -> W^T (bf16 N x K) in one launch.
// ---------------------------------------------------------------------------
__global__ __launch_bounds__(256) void cvtT_all_kernel(const float* __restrict__ W_la,
                                                       const float* __restrict__ W_v,
                                                       const float* __restrict__ W_proj,
                                                       __hip_bfloat16* __restrict__ Wcat,
                                                       __hip_bfloat16* __restrict__ WprojT) {
  __shared__ __hip_bfloat16 tile[64][66];
  const int z = blockIdx.z;
  const float* W = (z == 0) ? W_la : (z == 1) ? W_v : W_proj;
  __hip_bfloat16* WT = (z == 2) ? WprojT : Wcat + (size_t)z * C_ * C_;
  const int w = threadIdx.x >> 6, l = threadIdx.x & 63;
  const int n0 = blockIdx.x * 64, k0 = blockIdx.y * 64;
#pragma unroll
  for (int r = 0; r < 16; ++r) {
    const int k = k0 + w * 16 + r;
    tile[w * 16 + r][l] = __float2bfloat16(W[(size_t)k * C_ + n0 + l]);
  }
  __syncthreads();
#pragma unroll
  for (int r = 0; r < 16; ++r) {
    const int nn = w * 16 + r;
    WT[(size_t)(n0 + nn) * C_ + k0 + l] = tile[l][nn];
  }
}

// ---------------------------------------------------------------------------
// Combined input GEMM: [xl | xv] = x16(4096x1024) @ Wcat(2048x1024)^T.
// 128x128 tile, BK=32, m97 recipe. Grid (16, 32) = 512 blocks = 2/CU.
// ---------------------------------------------------------------------------
__global__ __launch_bounds__(256) void gemm_in_kernel(const __hip_bfloat16* __restrict__ A,
                                                      const __hip_bfloat16* __restrict__ BT,
                                                      float* __restrict__ C0,
                                                      float* __restrict__ C1) {
  __shared__ __hip_bfloat16 As[128 * 32];
  __shared__ __hip_bfloat16 Bs[128 * 32];
  const int tid = threadIdx.x;
  const int m0 = blockIdx.y * 128, n0 = blockIdx.x * 128;
  const int w = tid >> 6, l = tid & 63;
  const int n = l & 15, kg = l >> 4;
  const int m0w = (w & 1) * 64, n0w = (w >> 1) * 64;

  const int r0 = tid >> 2, o0 = (tid & 3) * 8;
  const __hip_bfloat16* ag0 = A + (size_t)(m0 + r0) * C_ + o0;
  const __hip_bfloat16* ag1 = A + (size_t)(m0 + 64 + r0) * C_ + o0;
  const __hip_bfloat16* bg0 = BT + (size_t)(n0 + r0) * C_ + o0;
  const __hip_bfloat16* bg1 = BT + (size_t)(n0 + 64 + r0) * C_ + o0;
  __hip_bfloat16* al0 = As + tid * 8;
  __hip_bfloat16* al1 = As + (256 + tid) * 8;
  __hip_bfloat16* bl0 = Bs + tid * 8;
  __hip_bfloat16* bl1 = Bs + (256 + tid) * 8;

  f32x4 acc[4][4];
#pragma unroll
  for (int i = 0; i < 4; ++i)
#pragma unroll
    for (int j = 0; j < 4; ++j) acc[i][j] = f32x4{0.f, 0.f, 0.f, 0.f};

  for (int k0 = 0; k0 < C_; k0 += 32) {
    gl_lds16(ag0 + k0, al0);
    gl_lds16(ag1 + k0, al1);
    gl_lds16(bg0 + k0, bl0);
    gl_lds16(bg1 + k0, bl1);
    __syncthreads();
    bf16x8 af[4], bf[4];
#pragma unroll
    for (int ms = 0; ms < 4; ++ms)
      af[ms] = *reinterpret_cast<const bf16x8*>(As + (m0w + ms * 16 + n) * 32 + kg * 8);
#pragma unroll
    for (int ns = 0; ns < 4; ++ns)
      bf[ns] = *reinterpret_cast<const bf16x8*>(Bs + (n0w + ns * 16 + n) * 32 + kg * 8);
#pragma unroll
    for (int ms = 0; ms < 4; ++ms)
#pragma unroll
      for (int ns = 0; ns < 4; ++ns)
        acc[ms][ns] = __builtin_amdgcn_mfma_f32_16x16x32_bf16(af[ms], bf[ns], acc[ms][ns], 0, 0, 0);
    __syncthreads();
  }

  float* Cb = (n0 < C_) ? C0 : C1;
  const int nc = (n0 < C_) ? n0 : n0 - C_;
#pragma unroll
  for (int ms = 0; ms < 4; ++ms) {
#pragma unroll
    for (int r = 0; r < 4; ++r) {
      const int row = m0 + m0w + ms * 16 + kg * 4 + r;
      float* cp = Cb + (size_t)row * C_ + nc + n0w + n;
#pragma unroll
      for (int ns = 0; ns < 4; ++ns) cp[ns * 16] = acc[ms][ns][r];
    }
  }
}

// ---------------------------------------------------------------------------
// Projection GEMM: out = y16(4096x1024) @ WprojT(1024x1024)^T, fp32 out.
// 64x128 tile -> grid (8, 64) = 512 blocks = 2/CU.
// ---------------------------------------------------------------------------
__global__ __launch_bounds__(256) void gemm_proj_kernel(const __hip_bfloat16* __restrict__ A,
                                                        const __hip_bfloat16* __restrict__ BT,
                                                        float* __restrict__ Cout) {
  __shared__ __hip_bfloat16 As[64 * 32];
  __shared__ __hip_bfloat16 Bs[128 * 32];
  const int tid = threadIdx.x;
  const int m0 = blockIdx.y * 64, n0 = blockIdx.x * 128;
  const int w = tid >> 6, l = tid & 63;
  const int n = l & 15, kg = l >> 4;

  const int r0 = tid >> 2, o0 = (tid & 3) * 8;
  const __hip_bfloat16* ag = A + (size_t)(m0 + r0) * C_ + o0;
  const __hip_bfloat16* bg0 = BT + (size_t)(n0 + r0) * C_ + o0;
  const __hip_bfloat16* bg1 = BT + (size_t)(n0 + 64 + r0) * C_ + o0;
  __hip_bfloat16* al = As + tid * 8;
  __hip_bfloat16* bl0 = Bs + tid * 8;
  __hip_bfloat16* bl1 = Bs + (256 + tid) * 8;

  f32x4 acc[4][2];
#pragma unroll
  for (int i = 0; i < 4; ++i)
#pragma unroll
    for (int j = 0; j < 2; ++j) acc[i][j] = f32x4{0.f, 0.f, 0.f, 0.f};

  for (int k0 = 0; k0 < C_; k0 += 32) {
    gl_lds16(ag + k0, al);
    gl_lds16(bg0 + k0, bl0);
    gl_lds16(bg1 + k0, bl1);
    __syncthreads();
    bf16x8 af[4], bf[2];
#pragma unroll
    for (int ms = 0; ms < 4; ++ms)
      af[ms] = *reinterpret_cast<const bf16x8*>(As + (ms * 16 + n) * 32 + kg * 8);
#pragma unroll
    for (int ns = 0; ns < 2; ++ns)
      bf[ns] = *reinterpret_cast<const bf16x8*>(Bs + (w * 32 + ns * 16 + n) * 32 + kg * 8);
#pragma unroll
    for (int ms = 0; ms < 4; ++ms)
#pragma unroll
      for (int ns = 0; ns < 2; ++ns)
        acc[ms][ns] = __builtin_amdgcn_mfma_f32_16x16x32_bf16(af[ms], bf[ns], acc[ms][ns], 0, 0, 0);
    __syncthreads();
  }

#pragma unroll
  for (int ms = 0; ms < 4; ++ms) {
#pragma unroll
    for (int r = 0; r < 4; ++r) {
      const int row = m0 + ms * 16 + kg * 4 + r;
      float* cp = Cout + (size_t)row * C_ + n0 + w * 32 + n;
#pragma unroll
      for (int ns = 0; ns < 2; ++ns) cp[ns * 16] = acc[ms][ns][r];
    }
  }
}

// ---------------------------------------------------------------------------
// EMA pass 1: per-(bh,chunk) local scan (zero initial state).
// ---------------------------------------------------------------------------
__global__ __launch_bounds__(256) void ema_local_kernel(const float* __restrict__ xl,
                                                        float* __restrict__ loc,
                                                        float* __restrict__ carr,
                                                        const float* __restrict__ la_coef) {
  const int c = blockIdx.x % SCN_;
  const int bh = blockIdx.x / SCN_;
  const int b = bh / NH_, h = bh % NH_;
  const int tid = threadIdx.x;
  const int t0 = c * SCL_;
  __shared__ float buf[SCL_ * HS_];  // 32 KB

  const float alpha = la_coef[h];
  const float onema = 1.0f - alpha;
  const float4* src4 = reinterpret_cast<const float4*>(xl + (size_t)b * T_ * C_ + h * HS_);

  float4* buf4 = reinterpret_cast<float4*>(buf);
#pragma unroll
  for (int i = 0; i < (SCL_ * HS_ / 4) / 256; ++i) {  // 8 iters
    const int idx = tid + i * 256;
    const int tt = idx >> 4, d4 = idx & 15;
    buf4[tt * 16 + d4] = src4[(size_t)(t0 + tt) * (C_ / 4) + d4];
  }
  __syncthreads();
  if (tid < 64) {
    const int d = tid;
    float c2 = 0.0f;
#pragma unroll 8
    for (int tt = 0; tt < SCL_; ++tt) {
      c2 = alpha * c2 + onema * buf[tt * HS_ + d];
      buf[tt * HS_ + d] = c2;
    }
    carr[(size_t)(bh * SCN_ + c) * HS_ + d] = c2;  // chunk-final
  }
  __syncthreads();
  float4* dst4 = reinterpret_cast<float4*>(loc + ((size_t)bh * T_ + t0) * HS_);
#pragma unroll
  for (int i = 0; i < (SCL_ * HS_ / 4) / 256; ++i) dst4[tid + i * 256] = buf4[tid + i * 256];
}

// ---------------------------------------------------------------------------
// EMA pass 2 (fused carry): combine chunk-finals (Horner), row-normalize,
// kb-scale, emit bf16 k in TILE-SLOT layout (BH, NT, g=hs>>3, key, 8).
// ---------------------------------------------------------------------------
__global__ __launch_bounds__(256) void ema_fix_norm_kernel(const float* __restrict__ loc,
                                                           const float* __restrict__ carr,
                                                           __hip_bfloat16* __restrict__ kb16,
                                                           const float* __restrict__ la_coef,
                                                           const float* __restrict__ kernel_beta) {
  const int c = blockIdx.x % SCN_;
  const int bh = blockIdx.x / SCN_;
  const int h = bh % NH_;
  const int w = threadIdx.x >> 6, l = threadIdx.x & 63;

  const float alpha = la_coef[h];
  const float aL = __powf(alpha, (float)SCL_);
  const float kbs = expf(fminf(kernel_beta[h] * 10.0f, 5.0f));

  float A = 0.0f;
  for (int cc = 0; cc < c; ++cc) A = aL * A + carr[(size_t)(bh * SCN_ + cc) * HS_ + l];

  const float* lp = loc + ((size_t)bh * T_ + c * SCL_ + w * 32) * HS_ + l;
  __hip_bfloat16* kt = kb16 + (size_t)bh * NT_ * TEL_;
  const int g = l >> 3, j = l & 7;

  float s = __powf(alpha, (float)(w * 32 + 1));
  for (int rr = 0; rr < 32; ++rr) {
    const int t = c * SCL_ + w * 32 + rr;
    float val = lp[rr * HS_] + s * A;
    float ss = val * val;
#pragma unroll
    for (int m = 32; m; m >>= 1) ss += __shfl_xor(ss, m);
    const int tile = t >> 6, key = t & 63;
    kt[(size_t)tile * TEL_ + (g * 64 + key) * 8 + j] = __float2bfloat16(val * (kbs / sqrtf(ss)));
    s *= alpha;
  }
}

// ---------------------------------------------------------------------------
// Build v, emit TILE-SLOT bf16 vt (BH, NT, kk=key>>3, hs, 8).
// ---------------------------------------------------------------------------
__global__ __launch_bounds__(256) void vprep_kernel(const float* __restrict__ xv,
                                                    __hip_bfloat16* __restrict__ vt,
                                                    const float* __restrict__ value_beta,
                                                    const float* __restrict__ v_coef) {
  const int tc = blockIdx.x % NT_;
  const int bh = blockIdx.x / NT_;
  const int h = bh % NH_, b = bh / NH_;
  const int t0 = tc * 64;
  const int w = threadIdx.x >> 6, l = threadIdx.x & 63;
  __shared__ __hip_bfloat16 tile[64][66];

  const float c = v_coef[h];
  const float vb = expf(value_beta[h] * 10.0f);

  for (int r = 0; r < 16; ++r) {
    const int tl = w * 16 + r;
    const int t = t0 + tl;
    const float* base = xv + ((size_t)b * T_ + t) * C_ + h * HS_ + l;
    const float cur = base[0];
    const float nxt = (t + 1 < T_) ? base[C_] : 0.0f;
    float val = nxt * (1.0f - c) + cur * c;
    float ssum = val * val;
#pragma unroll
    for (int m = 32; m; m >>= 1) ssum += __shfl_xor(ssum, m);
    tile[tl][l] = __float2bfloat16(val * (vb / sqrtf(ssum)));
  }
  __syncthreads();
  __hip_bfloat16* vtb = vt + (size_t)(bh * NT_ + tc) * TEL_;
  const int kk = l >> 3, j = l & 7;  // l = key
  for (int rr = 0; rr < 16; ++rr) {
    const int hs = w * 16 + rr;
    vtb[(kk * 64 + hs) * 8 + j] = tile[l][hs];
  }
}

// ---------------------------------------------------------------------------
// MFMA flash attention: slot-layout tiles, double-buffered LDS with
// CROSS-ITERATION PREFETCH (one barrier/tile; DMA(j+1) issued before
// compute(j), drained only at the next barrier -> latency hidden).
// No online max (|s| <= e^2).
// ---------------------------------------------------------------------------
__global__ __launch_bounds__(256) void attn_mfma_kernel(
    const __hip_bfloat16* __restrict__ kb,   // (BH, NT, g, key, 8) slot tiles
    const __hip_bfloat16* __restrict__ vt,   // (BH, NT, kk, hs, 8) slot tiles
    __hip_bfloat16* __restrict__ y) {        // (B, T, C) bf16
  __shared__ __hip_bfloat16 Ks[2][TEL_];
  __shared__ __hip_bfloat16 Vs[2][TEL_];
  __shared__ __hip_bfloat16 Ps[4][16 * 68];  // per-wave P, pad 68 (conflict-free)

  const int bh = blockIdx.y;
  const int b = bh / NH_, h = bh % NH_;
  const int qt = (NT_ - 1) - (int)blockIdx.x;  // longest first
  const int q0 = qt * 64;
  const int w = threadIdx.x >> 6;
  const int l = threadIdx.x & 63;
  const int n = l & 15;
  const int kg = l >> 4;
  const int query = q0 + w * 16 + n;
  const int lo = l * 8;  // per-lane 16B offset (elements)
  const int tb = bh * NT_;

  // Q B-fragments from global slot tile (once)
  bf16x8 qf0, qf1;
  {
    const __hip_bfloat16* qtile = kb + (size_t)(tb + qt) * TEL_;
    qf0 = *reinterpret_cast<const bf16x8*>(qtile + (kg * 64 + w * 16 + n) * 8);
    qf1 = *reinterpret_cast<const bf16x8*>(qtile + ((kg + 4) * 64 + w * 16 + n) * 8);
  }

  f32x4 accO[4];
#pragma unroll
  for (int i = 0; i < 4; ++i) accO[i] = f32x4{0.f, 0.f, 0.f, 0.f};
  float l_acc = 0.0f;

  __hip_bfloat16* Pw = Ps[w];
  int* Pwi = reinterpret_cast<int*>(Pw);

  // prologue: stage tile 0 into buffer 0 (wave w covers elements w*1024..+1023)
  {
    const size_t tbase = (size_t)tb * TEL_;
    gl_lds16(kb + tbase + w * 1024 + lo, &Ks[0][w * 1024 + lo]);
    gl_lds16(kb + tbase + w * 1024 + 512 + lo, &Ks[0][w * 1024 + 512 + lo]);
    gl_lds16(vt + tbase + w * 1024 + lo, &Vs[0][w * 1024 + lo]);
    gl_lds16(vt + tbase + w * 1024 + 512 + lo, &Vs[0][w * 1024 + 512 + lo]);
  }

  for (int jt = 0; jt <= qt; ++jt) {
    const int cur = jt & 1;
    // barrier: (a) per-wave vmcnt drain -> DMA(jt) complete;
    //          (b) all waves done computing jt-1 -> buf[cur^1] free.
    __syncthreads();
    if (jt < qt) {
      const size_t tbase = (size_t)(tb + jt + 1) * TEL_;
      const int nb = cur ^ 1;
      gl_lds16(kb + tbase + w * 1024 + lo, &Ks[nb][w * 1024 + lo]);
      gl_lds16(kb + tbase + w * 1024 + 512 + lo, &Ks[nb][w * 1024 + 512 + lo]);
      gl_lds16(vt + tbase + w * 1024 + lo, &Vs[nb][w * 1024 + lo]);
      gl_lds16(vt + tbase + w * 1024 + 512 + lo, &Vs[nb][w * 1024 + 512 + lo]);
    }

    const bool diag = (jt == qt);
    const __hip_bfloat16* Kss = Ks[cur];
    const __hip_bfloat16* Vss = Vs[cur];

    // ---- S^T = K @ Q^T ----
    f32x4 accS[4];
#pragma unroll
    for (int ms = 0; ms < 4; ++ms) {
      bf16x8 a0 = *reinterpret_cast<const bf16x8*>(Kss + (kg * 64 + ms * 16 + n) * 8);
      bf16x8 a1 = *reinterpret_cast<const bf16x8*>(Kss + ((kg + 4) * 64 + ms * 16 + n) * 8);
      f32x4 z{0.f, 0.f, 0.f, 0.f};
      z = __builtin_amdgcn_mfma_f32_16x16x32_bf16(a0, qf0, z, 0, 0, 0);
      accS[ms] = __builtin_amdgcn_mfma_f32_16x16x32_bf16(a1, qf1, z, 0, 0, 0);
    }

    // ---- exp + causal mask + row-sum; P to wave-local LDS ----
    float lsum = 0.0f;
    const int qq = w * 16 + n;
#pragma unroll
    for (int ms = 0; ms < 4; ++ms) {
      const int kbase = ms * 16 + kg * 4;
      float p[4];
#pragma unroll
      for (int r = 0; r < 4; ++r) {
        const float e = __expf(accS[ms][r]);
        p[r] = (!diag || (kbase + r < qq)) ? e : 0.0f;
        lsum += p[r];
      }
      const int po = n * 34 + ms * 8 + kg * 2;
      Pwi[po] = pack_bf16(p[0], p[1]);
      Pwi[po + 1] = pack_bf16(p[2], p[3]);
    }
    lsum += __shfl_xor(lsum, 16);
    lsum += __shfl_xor(lsum, 32);
    l_acc += lsum;

    // ---- O^T += V^T @ P^T ----
#pragma unroll
    for (int ks = 0; ks < 2; ++ks) {
      union { ushort4 u[2]; bf16x8 v; } pr;
      const __hip_bfloat16* pp = Pw + n * 68 + ks * 32 + kg * 8;
      pr.u[0] = *reinterpret_cast<const ushort4*>(pp);
      pr.u[1] = *reinterpret_cast<const ushort4*>(pp + 4);
#pragma unroll
      for (int mo = 0; mo < 4; ++mo) {
        bf16x8 av = *reinterpret_cast<const bf16x8*>(Vss + ((ks * 4 + kg) * 64 + mo * 16 + n) * 8);
        accO[mo] = __builtin_amdgcn_mfma_f32_16x16x32_bf16(av, pr.v, accO[mo], 0, 0, 0);
      }
    }
  }

  const float inv = (query == 0) ? 0.0f : 1.0f / l_acc;
  __hip_bfloat16* yb = y + ((size_t)b * T_ + query) * C_ + h * HS_;
#pragma unroll
  for (int mo = 0; mo < 4; ++mo) {
    int2 pkd;
    pkd.x = pack_bf16(accO[mo][0] * inv, accO[mo][1] * inv);
    pkd.y = pack_bf16(accO[mo][2] * inv, accO[mo][3] * inv);
    *reinterpret_cast<int2*>(yb + mo * 16 + kg * 4) = pkd;
  }
}

// ---------------------------------------------------------------------------
extern "C" void kernel_launch(void* const* d_in, const int* in_sizes, int n_in,
                              void* d_out, int out_size, void* d_ws, size_t ws_size,
                              hipStream_t stream) {
  const float* x           = (const float*)d_in[0];
  const float* W_la        = (const float*)d_in[1];
  const float* la_coef     = (const float*)d_in[2];
  const float* kernel_beta = (const float*)d_in[3];
  const float* value_beta  = (const float*)d_in[4];
  const float* W_v         = (const float*)d_in[5];
  const float* v_coef      = (const float*)d_in[6];
  const float* W_proj      = (const float*)d_in[7];
  float* out = (float*)d_out;

  char* wsb = (char*)d_ws;
  const size_t MB = 1024u * 1024u;
  __hip_bfloat16* x16    = (__hip_bfloat16*)(wsb);            // 8 MB
  __hip_bfloat16* Wcat   = (__hip_bfloat16*)(wsb + 8 * MB);   // 4 MB (W_laT | W_vT)
  __hip_bfloat16* WprojT = (__hip_bfloat16*)(wsb + 12 * MB);  // 2 MB
  float* carr            = (float*)(wsb + 14 * MB);           // 128 KB
  float* xl              = (float*)(wsb + 16 * MB);           // 16 MB
  float* xv              = (float*)(wsb + 32 * MB);           // 16 MB
  __hip_bfloat16* kb16   = (__hip_bfloat16*)(wsb + 48 * MB);  // 8 MB
  __hip_bfloat16* vt16   = (__hip_bfloat16*)(wsb + 56 * MB);  // 8 MB
  float* loc             = xv;                                 // reuse: xv dead after vprep
  __hip_bfloat16* y16    = (__hip_bfloat16*)(wsb + 16 * MB);  // aliases xl (dead after pass1)
  (void)ws_size; (void)in_sizes; (void)n_in; (void)out_size;

  const int M = B_ * T_;

  cvt_bf16_kernel<<<dim3((M * C_) / 2048), dim3(256), 0, stream>>>(x, x16);
  cvtT_all_kernel<<<dim3(C_ / 64, C_ / 64, 3), dim3(256), 0, stream>>>(W_la, W_v, W_proj, Wcat, WprojT);

  gemm_in_kernel<<<dim3(2 * C_ / 128, M / 128), dim3(256), 0, stream>>>(x16, Wcat, xl, xv);
  vprep_kernel<<<dim3(B_ * NH_ * NT_), dim3(256), 0, stream>>>(xv, vt16, value_beta, v_coef);
  ema_local_kernel<<<dim3(B_ * NH_ * SCN_), dim3(256), 0, stream>>>(xl, loc, carr, la_coef);
  ema_fix_norm_kernel<<<dim3(B_ * NH_ * SCN_), dim3(256), 0, stream>>>(loc, carr, kb16, la_coef, kernel_beta);
  attn_mfma_kernel<<<dim3(NT_, B_ * NH_), dim3(256), 0, stream>>>(kb16, vt16, y16);
  gemm_proj_kernel<<<dim3(C_ / 128, M / 64), dim3(256), 0, stream>>>(y16, WprojT, out);
}

// Round 10
// 246.061 us; speedup vs baseline: 1.0190x; 1.0190x over previous
//
#include <hip/hip_runtime.h>
#include <hip/hip_bf16.h>

#define B_  2
#define T_  2048
#define NH_ 16
#define HS_ 64
#define C_  1024
#define SCL_ 128              // EMA chunk length
#define SCN_ (T_ / SCL_)      // 16 chunks
#define NT_  (T_ / 64)        // 32 key/query tiles
#define TEL_ 4096             // elements per 64x64 tile

typedef __attribute__((ext_vector_type(8))) short bf16x8;
typedef __attribute__((ext_vector_type(4))) float f32x4;

__device__ inline int pack_bf16(float a, float b) {
  union { __hip_bfloat16 h; unsigned short u; } ua, ub;
  ua.h = __float2bfloat16(a);
  ub.h = __float2bfloat16(b);
  return (int)(((unsigned)ub.u << 16) | (unsigned)ua.u);
}

// async global->LDS 16B: global ptr is PER-LANE; LDS dest must equal
// wave-uniform base + lane*16. Callers pass per-lane g AND l = base+lane*16.
__device__ inline void gl_lds16(const __hip_bfloat16* g, __hip_bfloat16* l) {
  __builtin_amdgcn_global_load_lds(
      (const __attribute__((address_space(1))) unsigned int*)g,
      (__attribute__((address_space(3))) unsigned int*)l, 16, 0, 0);
}

// ---------------------------------------------------------------------------
// fp32 -> bf16 elementwise (8 elems/thread)
// ---------------------------------------------------------------------------
__global__ __launch_bounds__(256) void cvt_bf16_kernel(const float* __restrict__ in,
                                                       __hip_bfloat16* __restrict__ out) {
  const int i = (blockIdx.x * 256 + threadIdx.x) * 8;
  const float4 a = *reinterpret_cast<const float4*>(in + i);
  const float4 b = *reinterpret_cast<const float4*>(in + i + 4);
  union { int s[4]; int4 v; } u;
  u.s[0] = pack_bf16(a.x, a.y);
  u.s[1] = pack_bf16(a.z, a.w);
  u.s[2] = pack_bf16(b.x, b.y);
  u.s[3] = pack_bf16(b.z, b.w);
  *reinterpret_cast<int4*>(out + i) = u.v;
}

// ---------------------------------------------------------------------------
// All 3 weights (fp32 K x N) -> W^T (bf16 N x K) in one launch.
// ---------------------------------------------------------------------------
__global__ __launch_bounds__(256) void cvtT_all_kernel(const float* __restrict__ W_la,
                                                       const float* __restrict__ W_v,
                                                       const float* __restrict__ W_proj,
                                                       __hip_bfloat16* __restrict__ Wcat,
                                                       __hip_bfloat16* __restrict__ WprojT) {
  __shared__ __hip_bfloat16 tile[64][66];
  const int z = blockIdx.z;
  const float* W = (z == 0) ? W_la : (z == 1) ? W_v : W_proj;
  __hip_bfloat16* WT = (z == 2) ? WprojT : Wcat + (size_t)z * C_ * C_;
  const int w = threadIdx.x >> 6, l = threadIdx.x & 63;
  const int n0 = blockIdx.x * 64, k0 = blockIdx.y * 64;
#pragma unroll
  for (int r = 0; r < 16; ++r) {
    const int k = k0 + w * 16 + r;
    tile[w * 16 + r][l] = __float2bfloat16(W[(size_t)k * C_ + n0 + l]);
  }
  __syncthreads();
#pragma unroll
  for (int r = 0; r < 16; ++r) {
    const int nn = w * 16 + r;
    WT[(size_t)(n0 + nn) * C_ + k0 + l] = tile[l][nn];
  }
}

// ---------------------------------------------------------------------------
// Combined input GEMM: [xl | xv] = x16(4096x1024) @ Wcat(2048x1024)^T.
// ---------------------------------------------------------------------------
__global__ __launch_bounds__(256) void gemm_in_kernel(const __hip_bfloat16* __restrict__ A,
                                                      const __hip_bfloat16* __restrict__ BT,
                                                      float* __restrict__ C0,
                                                      float* __restrict__ C1) {
  __shared__ __hip_bfloat16 As[128 * 32];
  __shared__ __hip_bfloat16 Bs[128 * 32];
  const int tid = threadIdx.x;
  const int m0 = blockIdx.y * 128, n0 = blockIdx.x * 128;
  const int w = tid >> 6, l = tid & 63;
  const int n = l & 15, kg = l >> 4;
  const int m0w = (w & 1) * 64, n0w = (w >> 1) * 64;

  const int r0 = tid >> 2, o0 = (tid & 3) * 8;
  const __hip_bfloat16* ag0 = A + (size_t)(m0 + r0) * C_ + o0;
  const __hip_bfloat16* ag1 = A + (size_t)(m0 + 64 + r0) * C_ + o0;
  const __hip_bfloat16* bg0 = BT + (size_t)(n0 + r0) * C_ + o0;
  const __hip_bfloat16* bg1 = BT + (size_t)(n0 + 64 + r0) * C_ + o0;
  __hip_bfloat16* al0 = As + tid * 8;
  __hip_bfloat16* al1 = As + (256 + tid) * 8;
  __hip_bfloat16* bl0 = Bs + tid * 8;
  __hip_bfloat16* bl1 = Bs + (256 + tid) * 8;

  f32x4 acc[4][4];
#pragma unroll
  for (int i = 0; i < 4; ++i)
#pragma unroll
    for (int j = 0; j < 4; ++j) acc[i][j] = f32x4{0.f, 0.f, 0.f, 0.f};

  for (int k0 = 0; k0 < C_; k0 += 32) {
    gl_lds16(ag0 + k0, al0);
    gl_lds16(ag1 + k0, al1);
    gl_lds16(bg0 + k0, bl0);
    gl_lds16(bg1 + k0, bl1);
    __syncthreads();
    bf16x8 af[4], bf[4];
#pragma unroll
    for (int ms = 0; ms < 4; ++ms)
      af[ms] = *reinterpret_cast<const bf16x8*>(As + (m0w + ms * 16 + n) * 32 + kg * 8);
#pragma unroll
    for (int ns = 0; ns < 4; ++ns)
      bf[ns] = *reinterpret_cast<const bf16x8*>(Bs + (n0w + ns * 16 + n) * 32 + kg * 8);
#pragma unroll
    for (int ms = 0; ms < 4; ++ms)
#pragma unroll
      for (int ns = 0; ns < 4; ++ns)
        acc[ms][ns] = __builtin_amdgcn_mfma_f32_16x16x32_bf16(af[ms], bf[ns], acc[ms][ns], 0, 0, 0);
    __syncthreads();
  }

  float* Cb = (n0 < C_) ? C0 : C1;
  const int nc = (n0 < C_) ? n0 : n0 - C_;
#pragma unroll
  for (int ms = 0; ms < 4; ++ms) {
#pragma unroll
    for (int r = 0; r < 4; ++r) {
      const int row = m0 + m0w + ms * 16 + kg * 4 + r;
      float* cp = Cb + (size_t)row * C_ + nc + n0w + n;
#pragma unroll
      for (int ns = 0; ns < 4; ++ns) cp[ns * 16] = acc[ms][ns][r];
    }
  }
}

// ---------------------------------------------------------------------------
// Projection GEMM: out = y16(4096x1024) @ WprojT(1024x1024)^T, fp32 out.
// ---------------------------------------------------------------------------
__global__ __launch_bounds__(256) void gemm_proj_kernel(const __hip_bfloat16* __restrict__ A,
                                                        const __hip_bfloat16* __restrict__ BT,
                                                        float* __restrict__ Cout) {
  __shared__ __hip_bfloat16 As[64 * 32];
  __shared__ __hip_bfloat16 Bs[128 * 32];
  const int tid = threadIdx.x;
  const int m0 = blockIdx.y * 64, n0 = blockIdx.x * 128;
  const int w = tid >> 6, l = tid & 63;
  const int n = l & 15, kg = l >> 4;

  const int r0 = tid >> 2, o0 = (tid & 3) * 8;
  const __hip_bfloat16* ag = A + (size_t)(m0 + r0) * C_ + o0;
  const __hip_bfloat16* bg0 = BT + (size_t)(n0 + r0) * C_ + o0;
  const __hip_bfloat16* bg1 = BT + (size_t)(n0 + 64 + r0) * C_ + o0;
  __hip_bfloat16* al = As + tid * 8;
  __hip_bfloat16* bl0 = Bs + tid * 8;
  __hip_bfloat16* bl1 = Bs + (256 + tid) * 8;

  f32x4 acc[4][2];
#pragma unroll
  for (int i = 0; i < 4; ++i)
#pragma unroll
    for (int j = 0; j < 2; ++j) acc[i][j] = f32x4{0.f, 0.f, 0.f, 0.f};

  for (int k0 = 0; k0 < C_; k0 += 32) {
    gl_lds16(ag + k0, al);
    gl_lds16(bg0 + k0, bl0);
    gl_lds16(bg1 + k0, bl1);
    __syncthreads();
    bf16x8 af[4], bf[2];
#pragma unroll
    for (int ms = 0; ms < 4; ++ms)
      af[ms] = *reinterpret_cast<const bf16x8*>(As + (ms * 16 + n) * 32 + kg * 8);
#pragma unroll
    for (int ns = 0; ns < 2; ++ns)
      bf[ns] = *reinterpret_cast<const bf16x8*>(Bs + (w * 32 + ns * 16 + n) * 32 + kg * 8);
#pragma unroll
    for (int ms = 0; ms < 4; ++ms)
#pragma unroll
      for (int ns = 0; ns < 2; ++ns)
        acc[ms][ns] = __builtin_amdgcn_mfma_f32_16x16x32_bf16(af[ms], bf[ns], acc[ms][ns], 0, 0, 0);
    __syncthreads();
  }

#pragma unroll
  for (int ms = 0; ms < 4; ++ms) {
#pragma unroll
    for (int r = 0; r < 4; ++r) {
      const int row = m0 + ms * 16 + kg * 4 + r;
      float* cp = Cout + (size_t)row * C_ + n0 + w * 32 + n;
#pragma unroll
      for (int ns = 0; ns < 2; ++ns) cp[ns * 16] = acc[ms][ns][r];
    }
  }
}

// ---------------------------------------------------------------------------
// EMA pass 1: per-(bh,chunk) local scan (zero initial state).
// ---------------------------------------------------------------------------
__global__ __launch_bounds__(256) void ema_local_kernel(const float* __restrict__ xl,
                                                        float* __restrict__ loc,
                                                        float* __restrict__ carr,
                                                        const float* __restrict__ la_coef) {
  const int c = blockIdx.x % SCN_;
  const int bh = blockIdx.x / SCN_;
  const int b = bh / NH_, h = bh % NH_;
  const int tid = threadIdx.x;
  const int t0 = c * SCL_;
  __shared__ float buf[SCL_ * HS_];  // 32 KB

  const float alpha = la_coef[h];
  const float onema = 1.0f - alpha;
  const float4* src4 = reinterpret_cast<const float4*>(xl + (size_t)b * T_ * C_ + h * HS_);

  float4* buf4 = reinterpret_cast<float4*>(buf);
#pragma unroll
  for (int i = 0; i < (SCL_ * HS_ / 4) / 256; ++i) {  // 8 iters
    const int idx = tid + i * 256;
    const int tt = idx >> 4, d4 = idx & 15;
    buf4[tt * 16 + d4] = src4[(size_t)(t0 + tt) * (C_ / 4) + d4];
  }
  __syncthreads();
  if (tid < 64) {
    const int d = tid;
    float c2 = 0.0f;
#pragma unroll 8
    for (int tt = 0; tt < SCL_; ++tt) {
      c2 = alpha * c2 + onema * buf[tt * HS_ + d];
      buf[tt * HS_ + d] = c2;
    }
    carr[(size_t)(bh * SCN_ + c) * HS_ + d] = c2;  // chunk-final
  }
  __syncthreads();
  float4* dst4 = reinterpret_cast<float4*>(loc + ((size_t)bh * T_ + t0) * HS_);
#pragma unroll
  for (int i = 0; i < (SCL_ * HS_ / 4) / 256; ++i) dst4[tid + i * 256] = buf4[tid + i * 256];
}

// ---------------------------------------------------------------------------
// EMA pass 2 (fused carry): combine chunk-finals (Horner), row-normalize,
// kb-scale, emit bf16 k in TILE-SLOT layout (BH, NT, g=hs>>3, key, 8).
// ---------------------------------------------------------------------------
__global__ __launch_bounds__(256) void ema_fix_norm_kernel(const float* __restrict__ loc,
                                                           const float* __restrict__ carr,
                                                           __hip_bfloat16* __restrict__ kb16,
                                                           const float* __restrict__ la_coef,
                                                           const float* __restrict__ kernel_beta) {
  const int c = blockIdx.x % SCN_;
  const int bh = blockIdx.x / SCN_;
  const int h = bh % NH_;
  const int w = threadIdx.x >> 6, l = threadIdx.x & 63;

  const float alpha = la_coef[h];
  const float aL = __powf(alpha, (float)SCL_);
  const float kbs = expf(fminf(kernel_beta[h] * 10.0f, 5.0f));

  float A = 0.0f;
  for (int cc = 0; cc < c; ++cc) A = aL * A + carr[(size_t)(bh * SCN_ + cc) * HS_ + l];

  const float* lp = loc + ((size_t)bh * T_ + c * SCL_ + w * 32) * HS_ + l;
  __hip_bfloat16* kt = kb16 + (size_t)bh * NT_ * TEL_;
  const int g = l >> 3, j = l & 7;

  float s = __powf(alpha, (float)(w * 32 + 1));
  for (int rr = 0; rr < 32; ++rr) {
    const int t = c * SCL_ + w * 32 + rr;
    float val = lp[rr * HS_] + s * A;
    float ss = val * val;
#pragma unroll
    for (int m = 32; m; m >>= 1) ss += __shfl_xor(ss, m);
    const int tile = t >> 6, key = t & 63;
    kt[(size_t)tile * TEL_ + (g * 64 + key) * 8 + j] = __float2bfloat16(val * (kbs / sqrtf(ss)));
    s *= alpha;
  }
}

// ---------------------------------------------------------------------------
// Build v, emit TILE-SLOT bf16 vt (BH, NT, kk=key>>3, hs, 8).
// ---------------------------------------------------------------------------
__global__ __launch_bounds__(256) void vprep_kernel(const float* __restrict__ xv,
                                                    __hip_bfloat16* __restrict__ vt,
                                                    const float* __restrict__ value_beta,
                                                    const float* __restrict__ v_coef) {
  const int tc = blockIdx.x % NT_;
  const int bh = blockIdx.x / NT_;
  const int h = bh % NH_, b = bh / NH_;
  const int t0 = tc * 64;
  const int w = threadIdx.x >> 6, l = threadIdx.x & 63;
  __shared__ __hip_bfloat16 tile[64][66];

  const float c = v_coef[h];
  const float vb = expf(value_beta[h] * 10.0f);

  for (int r = 0; r < 16; ++r) {
    const int tl = w * 16 + r;
    const int t = t0 + tl;
    const float* base = xv + ((size_t)b * T_ + t) * C_ + h * HS_ + l;
    const float cur = base[0];
    const float nxt = (t + 1 < T_) ? base[C_] : 0.0f;
    float val = nxt * (1.0f - c) + cur * c;
    float ssum = val * val;
#pragma unroll
    for (int m = 32; m; m >>= 1) ssum += __shfl_xor(ssum, m);
    tile[tl][l] = __float2bfloat16(val * (vb / sqrtf(ssum)));
  }
  __syncthreads();
  __hip_bfloat16* vtb = vt + (size_t)(bh * NT_ + tc) * TEL_;
  const int kk = l >> 3, j = l & 7;  // l = key
  for (int rr = 0; rr < 16; ++rr) {
    const int hs = w * 16 + rr;
    vtb[(kk * 64 + hs) * 8 + j] = tile[l][hs];
  }
}

// ---------------------------------------------------------------------------
// MFMA flash attention: 128 queries/block (2 q-tiles), single-buffered LDS
// (24.7 KB -> ~6 blocks/CU), slot layout (0 conflicts). Each staged K/V tile
// serves 2 query strips per wave -> half the staging of the 64-q version.
// No online max (|s| <= e^2).
// ---------------------------------------------------------------------------
struct StripState {
  bf16x8 qf0, qf1;
  f32x4 accO[4];
  float l_acc;
};

__device__ inline void strip_compute(const __hip_bfloat16* Kss, const __hip_bfloat16* Vss,
                                     int* Pwi, const __hip_bfloat16* Pw,
                                     StripState& st, bool diag, int n, int kg) {
  // ---- S^T = K @ Q^T ----
  f32x4 accS[4];
#pragma unroll
  for (int ms = 0; ms < 4; ++ms) {
    bf16x8 a0 = *reinterpret_cast<const bf16x8*>(Kss + (kg * 64 + ms * 16 + n) * 8);
    bf16x8 a1 = *reinterpret_cast<const bf16x8*>(Kss + ((kg + 4) * 64 + ms * 16 + n) * 8);
    f32x4 z{0.f, 0.f, 0.f, 0.f};
    z = __builtin_amdgcn_mfma_f32_16x16x32_bf16(a0, st.qf0, z, 0, 0, 0);
    accS[ms] = __builtin_amdgcn_mfma_f32_16x16x32_bf16(a1, st.qf1, z, 0, 0, 0);
  }
  // ---- exp + (diag) mask + row-sum; P to wave-local LDS ----
  float lsum = 0.0f;
#pragma unroll
  for (int ms = 0; ms < 4; ++ms) {
    const int kbase = ms * 16 + kg * 4;
    float p[4];
#pragma unroll
    for (int r = 0; r < 4; ++r) {
      const float e = __expf(accS[ms][r]);
      p[r] = (!diag || (kbase + r < n + 0)) ? e : 0.0f;  // qq within tile = n (w-strip base handled by caller? no: qq = w*16+n)
      lsum += p[r];
    }
    const int po = n * 34 + ms * 8 + kg * 2;
    Pwi[po] = pack_bf16(p[0], p[1]);
    Pwi[po + 1] = pack_bf16(p[2], p[3]);
  }
  lsum += __shfl_xor(lsum, 16);
  lsum += __shfl_xor(lsum, 32);
  st.l_acc += lsum;
  // ---- O^T += V^T @ P^T ----
#pragma unroll
  for (int ks = 0; ks < 2; ++ks) {
    union { ushort4 u[2]; bf16x8 v; } pr;
    const __hip_bfloat16* pp = Pw + n * 68 + ks * 32 + kg * 8;
    pr.u[0] = *reinterpret_cast<const ushort4*>(pp);
    pr.u[1] = *reinterpret_cast<const ushort4*>(pp + 4);
#pragma unroll
    for (int mo = 0; mo < 4; ++mo) {
      bf16x8 av = *reinterpret_cast<const bf16x8*>(Vss + ((ks * 4 + kg) * 64 + mo * 16 + n) * 8);
      st.accO[mo] = __builtin_amdgcn_mfma_f32_16x16x32_bf16(av, pr.v, st.accO[mo], 0, 0, 0);
    }
  }
}

// NOTE on the mask above: the within-tile query index is qq = w*16 + n, not n.
// We bake w*16 into the comparison by shifting kbase at the call site is not
// possible (kbase is loop-internal), so the diag call passes a corrected Kss
// pointer? No -- simplest correct approach: specialize via template-free
// parameter. We pass qq and compare kbase + r < qq.
__device__ inline void strip_compute_q(const __hip_bfloat16* Kss, const __hip_bfloat16* Vss,
                                       int* Pwi, const __hip_bfloat16* Pw,
                                       StripState& st, bool diag, int qq, int n, int kg) {
  f32x4 accS[4];
#pragma unroll
  for (int ms = 0; ms < 4; ++ms) {
    bf16x8 a0 = *reinterpret_cast<const bf16x8*>(Kss + (kg * 64 + ms * 16 + n) * 8);
    bf16x8 a1 = *reinterpret_cast<const bf16x8*>(Kss + ((kg + 4) * 64 + ms * 16 + n) * 8);
    f32x4 z{0.f, 0.f, 0.f, 0.f};
    z = __builtin_amdgcn_mfma_f32_16x16x32_bf16(a0, st.qf0, z, 0, 0, 0);
    accS[ms] = __builtin_amdgcn_mfma_f32_16x16x32_bf16(a1, st.qf1, z, 0, 0, 0);
  }
  float lsum = 0.0f;
#pragma unroll
  for (int ms = 0; ms < 4; ++ms) {
    const int kbase = ms * 16 + kg * 4;
    float p[4];
#pragma unroll
    for (int r = 0; r < 4; ++r) {
      const float e = __expf(accS[ms][r]);
      p[r] = (!diag || (kbase + r < qq)) ? e : 0.0f;
      lsum += p[r];
    }
    const int po = n * 34 + ms * 8 + kg * 2;
    Pwi[po] = pack_bf16(p[0], p[1]);
    Pwi[po + 1] = pack_bf16(p[2], p[3]);
  }
  lsum += __shfl_xor(lsum, 16);
  lsum += __shfl_xor(lsum, 32);
  st.l_acc += lsum;
#pragma unroll
  for (int ks = 0; ks < 2; ++ks) {
    union { ushort4 u[2]; bf16x8 v; } pr;
    const __hip_bfloat16* pp = Pw + n * 68 + ks * 32 + kg * 8;
    pr.u[0] = *reinterpret_cast<const ushort4*>(pp);
    pr.u[1] = *reinterpret_cast<const ushort4*>(pp + 4);
#pragma unroll
    for (int mo = 0; mo < 4; ++mo) {
      bf16x8 av = *reinterpret_cast<const bf16x8*>(Vss + ((ks * 4 + kg) * 64 + mo * 16 + n) * 8);
      st.accO[mo] = __builtin_amdgcn_mfma_f32_16x16x32_bf16(av, pr.v, st.accO[mo], 0, 0, 0);
    }
  }
}

__global__ __launch_bounds__(256) void attn_mfma_kernel(
    const __hip_bfloat16* __restrict__ kb,   // (BH, NT, g, key, 8) slot tiles
    const __hip_bfloat16* __restrict__ vt,   // (BH, NT, kk, hs, 8) slot tiles
    __hip_bfloat16* __restrict__ y) {        // (B, T, C) bf16
  __shared__ __hip_bfloat16 Ks[TEL_];
  __shared__ __hip_bfloat16 Vs[TEL_];
  __shared__ __hip_bfloat16 Ps[4][16 * 68];  // per-wave P, pad 68 (conflict-free)

  const int bh = blockIdx.y;
  const int b = bh / NH_, h = bh % NH_;
  const int p = (NT_ / 2 - 1) - (int)blockIdx.x;  // pair index, longest first
  const int ta = 2 * p, tb_ = 2 * p + 1;          // the two query tiles
  const int w = threadIdx.x >> 6;
  const int l = threadIdx.x & 63;
  const int n = l & 15;
  const int kg = l >> 4;
  const int lo = l * 8;  // per-lane 16B offset (elements)
  const int tbase_bh = bh * NT_;
  const int qq = w * 16 + n;  // within-tile query index

  StripState sa, sb;
  {
    const __hip_bfloat16* qta = kb + (size_t)(tbase_bh + ta) * TEL_;
    sa.qf0 = *reinterpret_cast<const bf16x8*>(qta + (kg * 64 + qq) * 8);
    sa.qf1 = *reinterpret_cast<const bf16x8*>(qta + ((kg + 4) * 64 + qq) * 8);
    const __hip_bfloat16* qtb = kb + (size_t)(tbase_bh + tb_) * TEL_;
    sb.qf0 = *reinterpret_cast<const bf16x8*>(qtb + (kg * 64 + qq) * 8);
    sb.qf1 = *reinterpret_cast<const bf16x8*>(qtb + ((kg + 4) * 64 + qq) * 8);
  }
#pragma unroll
  for (int i = 0; i < 4; ++i) {
    sa.accO[i] = f32x4{0.f, 0.f, 0.f, 0.f};
    sb.accO[i] = f32x4{0.f, 0.f, 0.f, 0.f};
  }
  sa.l_acc = 0.0f;
  sb.l_acc = 0.0f;

  __hip_bfloat16* Pw = Ps[w];
  int* Pwi = reinterpret_cast<int*>(Pw);

  for (int jt = 0; jt <= tb_; ++jt) {
    __syncthreads();  // previous compute done -> safe to overwrite tiles
    {
      const size_t tg = (size_t)(tbase_bh + jt) * TEL_;
      gl_lds16(kb + tg + w * 1024 + lo, &Ks[w * 1024 + lo]);
      gl_lds16(kb + tg + w * 1024 + 512 + lo, &Ks[w * 1024 + 512 + lo]);
      gl_lds16(vt + tg + w * 1024 + lo, &Vs[w * 1024 + lo]);
      gl_lds16(vt + tg + w * 1024 + 512 + lo, &Vs[w * 1024 + 512 + lo]);
    }
    __syncthreads();  // DMA drained

    // strip B (tile tb_): participates for all jt; diag at jt == tb_
    strip_compute_q(Ks, Vs, Pwi, Pw, sb, jt == tb_, qq, n, kg);
    // strip A (tile ta): participates for jt <= ta; diag at jt == ta
    if (jt <= ta) strip_compute_q(Ks, Vs, Pwi, Pw, sa, jt == ta, qq, n, kg);
  }

  // ---- epilogue ----
  {
    const int query = ta * 64 + qq;
    const float inv = (query == 0) ? 0.0f : 1.0f / sa.l_acc;
    __hip_bfloat16* yb = y + ((size_t)b * T_ + query) * C_ + h * HS_;
#pragma unroll
    for (int mo = 0; mo < 4; ++mo) {
      int2 pkd;
      pkd.x = pack_bf16(sa.accO[mo][0] * inv, sa.accO[mo][1] * inv);
      pkd.y = pack_bf16(sa.accO[mo][2] * inv, sa.accO[mo][3] * inv);
      *reinterpret_cast<int2*>(yb + mo * 16 + kg * 4) = pkd;
    }
  }
  {
    const int query = tb_ * 64 + qq;
    const float inv = 1.0f / sb.l_acc;  // query >= 64 here, never 0
    __hip_bfloat16* yb = y + ((size_t)b * T_ + query) * C_ + h * HS_;
#pragma unroll
    for (int mo = 0; mo < 4; ++mo) {
      int2 pkd;
      pkd.x = pack_bf16(sb.accO[mo][0] * inv, sb.accO[mo][1] * inv);
      pkd.y = pack_bf16(sb.accO[mo][2] * inv, sb.accO[mo][3] * inv);
      *reinterpret_cast<int2*>(yb + mo * 16 + kg * 4) = pkd;
    }
  }
}

// ---------------------------------------------------------------------------
extern "C" void kernel_launch(void* const* d_in, const int* in_sizes, int n_in,
                              void* d_out, int out_size, void* d_ws, size_t ws_size,
                              hipStream_t stream) {
  const float* x           = (const float*)d_in[0];
  const float* W_la        = (const float*)d_in[1];
  const float* la_coef     = (const float*)d_in[2];
  const float* kernel_beta = (const float*)d_in[3];
  const float* value_beta  = (const float*)d_in[4];
  const float* W_v         = (const float*)d_in[5];
  const float* v_coef      = (const float*)d_in[6];
  const float* W_proj      = (const float*)d_in[7];
  float* out = (float*)d_out;

  char* wsb = (char*)d_ws;
  const size_t MB = 1024u * 1024u;
  __hip_bfloat16* x16    = (__hip_bfloat16*)(wsb);            // 8 MB
  __hip_bfloat16* Wcat   = (__hip_bfloat16*)(wsb + 8 * MB);   // 4 MB (W_laT | W_vT)
  __hip_bfloat16* WprojT = (__hip_bfloat16*)(wsb + 12 * MB);  // 2 MB
  float* carr            = (float*)(wsb + 14 * MB);           // 128 KB
  float* xl              = (float*)(wsb + 16 * MB);           // 16 MB
  float* xv              = (float*)(wsb + 32 * MB);           // 16 MB
  __hip_bfloat16* kb16   = (__hip_bfloat16*)(wsb + 48 * MB);  // 8 MB
  __hip_bfloat16* vt16   = (__hip_bfloat16*)(wsb + 56 * MB);  // 8 MB
  float* loc             = xv;                                 // reuse: xv dead after vprep
  __hip_bfloat16* y16    = (__hip_bfloat16*)(wsb + 16 * MB);  // aliases xl (dead after pass1)
  (void)ws_size; (void)in_sizes; (void)n_in; (void)out_size;

  const int M = B_ * T_;

  cvt_bf16_kernel<<<dim3((M * C_) / 2048), dim3(256), 0, stream>>>(x, x16);
  cvtT_all_kernel<<<dim3(C_ / 64, C_ / 64, 3), dim3(256), 0, stream>>>(W_la, W_v, W_proj, Wcat, WprojT);

  gemm_in_kernel<<<dim3(2 * C_ / 128, M / 128), dim3(256), 0, stream>>>(x16, Wcat, xl, xv);
  vprep_kernel<<<dim3(B_ * NH_ * NT_), dim3(256), 0, stream>>>(xv, vt16, value_beta, v_coef);
  ema_local_kernel<<<dim3(B_ * NH_ * SCN_), dim3(256), 0, stream>>>(xl, loc, carr, la_coef);
  ema_fix_norm_kernel<<<dim3(B_ * NH_ * SCN_), dim3(256), 0, stream>>>(loc, carr, kb16, la_coef, kernel_beta);
  attn_mfma_kernel<<<dim3(NT_ / 2, B_ * NH_), dim3(256), 0, stream>>>(kb16, vt16, y16);
  gemm_proj_kernel<<<dim3(C_ / 128, M / 64), dim3(256), 0, stream>>>(y16, WprojT, out);
}

// Round 11
// 222.468 us; speedup vs baseline: 1.1271x; 1.1060x over previous
//
#include <hip/hip_runtime.h>
#include <hip/hip_bf16.h>

#define B_  2
#define T_  2048
#define NH_ 16
#define HS_ 64
#define C_  1024
#define SCL_ 128              // EMA chunk length
#define SCN_ (T_ / SCL_)      // 16 chunks
#define NT_  (T_ / 64)        // 32 key/query tiles
#define TEL_ 4096             // elements per 64x64 tile

typedef __attribute__((ext_vector_type(8))) short bf16x8;
typedef __attribute__((ext_vector_type(4))) float f32x4;

__device__ inline int pack_bf16(float a, float b) {
  union { __hip_bfloat16 h; unsigned short u; } ua, ub;
  ua.h = __float2bfloat16(a);
  ub.h = __float2bfloat16(b);
  return (int)(((unsigned)ub.u << 16) | (unsigned)ua.u);
}

// async global->LDS 16B: global ptr is PER-LANE; LDS dest must equal
// wave-uniform base + lane*16. Callers pass per-lane g AND l = base+lane*16.
__device__ inline void gl_lds16(const __hip_bfloat16* g, __hip_bfloat16* l) {
  __builtin_amdgcn_global_load_lds(
      (const __attribute__((address_space(1))) unsigned int*)g,
      (__attribute__((address_space(3))) unsigned int*)l, 16, 0, 0);
}

// ---------------------------------------------------------------------------
// fp32 -> bf16 elementwise (8 elems/thread)
// ---------------------------------------------------------------------------
__global__ __launch_bounds__(256) void cvt_bf16_kernel(const float* __restrict__ in,
                                                       __hip_bfloat16* __restrict__ out) {
  const int i = (blockIdx.x * 256 + threadIdx.x) * 8;
  const float4 a = *reinterpret_cast<const float4*>(in + i);
  const float4 b = *reinterpret_cast<const float4*>(in + i + 4);
  union { int s[4]; int4 v; } u;
  u.s[0] = pack_bf16(a.x, a.y);
  u.s[1] = pack_bf16(a.z, a.w);
  u.s[2] = pack_bf16(b.x, b.y);
  u.s[3] = pack_bf16(b.z, b.w);
  *reinterpret_cast<int4*>(out + i) = u.v;
}

// ---------------------------------------------------------------------------
// All 3 weights (fp32 K x N) -> W^T (bf16 N x K) in one launch.
// ---------------------------------------------------------------------------
__global__ __launch_bounds__(256) void cvtT_all_kernel(const float* __restrict__ W_la,
                                                       const float* __restrict__ W_v,
                                                       const float* __restrict__ W_proj,
                                                       __hip_bfloat16* __restrict__ Wcat,
                                                       __hip_bfloat16* __restrict__ WprojT) {
  __shared__ __hip_bfloat16 tile[64][66];
  const int z = blockIdx.z;
  const float* W = (z == 0) ? W_la : (z == 1) ? W_v : W_proj;
  __hip_bfloat16* WT = (z == 2) ? WprojT : Wcat + (size_t)z * C_ * C_;
  const int w = threadIdx.x >> 6, l = threadIdx.x & 63;
  const int n0 = blockIdx.x * 64, k0 = blockIdx.y * 64;
#pragma unroll
  for (int r = 0; r < 16; ++r) {
    const int k = k0 + w * 16 + r;
    tile[w * 16 + r][l] = __float2bfloat16(W[(size_t)k * C_ + n0 + l]);
  }
  __syncthreads();
#pragma unroll
  for (int r = 0; r < 16; ++r) {
    const int nn = w * 16 + r;
    WT[(size_t)(n0 + nn) * C_ + k0 + l] = tile[l][nn];
  }
}

// ---------------------------------------------------------------------------
// Combined input GEMM: [xl | xv] = x16(4096x1024) @ Wcat(2048x1024)^T.
// ---------------------------------------------------------------------------
__global__ __launch_bounds__(256) void gemm_in_kernel(const __hip_bfloat16* __restrict__ A,
                                                      const __hip_bfloat16* __restrict__ BT,
                                                      float* __restrict__ C0,
                                                      float* __restrict__ C1) {
  __shared__ __hip_bfloat16 As[128 * 32];
  __shared__ __hip_bfloat16 Bs[128 * 32];
  const int tid = threadIdx.x;
  const int m0 = blockIdx.y * 128, n0 = blockIdx.x * 128;
  const int w = tid >> 6, l = tid & 63;
  const int n = l & 15, kg = l >> 4;
  const int m0w = (w & 1) * 64, n0w = (w >> 1) * 64;

  const int r0 = tid >> 2, o0 = (tid & 3) * 8;
  const __hip_bfloat16* ag0 = A + (size_t)(m0 + r0) * C_ + o0;
  const __hip_bfloat16* ag1 = A + (size_t)(m0 + 64 + r0) * C_ + o0;
  const __hip_bfloat16* bg0 = BT + (size_t)(n0 + r0) * C_ + o0;
  const __hip_bfloat16* bg1 = BT + (size_t)(n0 + 64 + r0) * C_ + o0;
  __hip_bfloat16* al0 = As + tid * 8;
  __hip_bfloat16* al1 = As + (256 + tid) * 8;
  __hip_bfloat16* bl0 = Bs + tid * 8;
  __hip_bfloat16* bl1 = Bs + (256 + tid) * 8;

  f32x4 acc[4][4];
#pragma unroll
  for (int i = 0; i < 4; ++i)
#pragma unroll
    for (int j = 0; j < 4; ++j) acc[i][j] = f32x4{0.f, 0.f, 0.f, 0.f};

  for (int k0 = 0; k0 < C_; k0 += 32) {
    gl_lds16(ag0 + k0, al0);
    gl_lds16(ag1 + k0, al1);
    gl_lds16(bg0 + k0, bl0);
    gl_lds16(bg1 + k0, bl1);
    __syncthreads();
    bf16x8 af[4], bf[4];
#pragma unroll
    for (int ms = 0; ms < 4; ++ms)
      af[ms] = *reinterpret_cast<const bf16x8*>(As + (m0w + ms * 16 + n) * 32 + kg * 8);
#pragma unroll
    for (int ns = 0; ns < 4; ++ns)
      bf[ns] = *reinterpret_cast<const bf16x8*>(Bs + (n0w + ns * 16 + n) * 32 + kg * 8);
#pragma unroll
    for (int ms = 0; ms < 4; ++ms)
#pragma unroll
      for (int ns = 0; ns < 4; ++ns)
        acc[ms][ns] = __builtin_amdgcn_mfma_f32_16x16x32_bf16(af[ms], bf[ns], acc[ms][ns], 0, 0, 0);
    __syncthreads();
  }

  float* Cb = (n0 < C_) ? C0 : C1;
  const int nc = (n0 < C_) ? n0 : n0 - C_;
#pragma unroll
  for (int ms = 0; ms < 4; ++ms) {
#pragma unroll
    for (int r = 0; r < 4; ++r) {
      const int row = m0 + m0w + ms * 16 + kg * 4 + r;
      float* cp = Cb + (size_t)row * C_ + nc + n0w + n;
#pragma unroll
      for (int ns = 0; ns < 4; ++ns) cp[ns * 16] = acc[ms][ns][r];
    }
  }
}

// ---------------------------------------------------------------------------
// Projection GEMM: out = y16(4096x1024) @ WprojT(1024x1024)^T, fp32 out.
// ---------------------------------------------------------------------------
__global__ __launch_bounds__(256) void gemm_proj_kernel(const __hip_bfloat16* __restrict__ A,
                                                        const __hip_bfloat16* __restrict__ BT,
                                                        float* __restrict__ Cout) {
  __shared__ __hip_bfloat16 As[64 * 32];
  __shared__ __hip_bfloat16 Bs[128 * 32];
  const int tid = threadIdx.x;
  const int m0 = blockIdx.y * 64, n0 = blockIdx.x * 128;
  const int w = tid >> 6, l = tid & 63;
  const int n = l & 15, kg = l >> 4;

  const int r0 = tid >> 2, o0 = (tid & 3) * 8;
  const __hip_bfloat16* ag = A + (size_t)(m0 + r0) * C_ + o0;
  const __hip_bfloat16* bg0 = BT + (size_t)(n0 + r0) * C_ + o0;
  const __hip_bfloat16* bg1 = BT + (size_t)(n0 + 64 + r0) * C_ + o0;
  __hip_bfloat16* al = As + tid * 8;
  __hip_bfloat16* bl0 = Bs + tid * 8;
  __hip_bfloat16* bl1 = Bs + (256 + tid) * 8;

  f32x4 acc[4][2];
#pragma unroll
  for (int i = 0; i < 4; ++i)
#pragma unroll
    for (int j = 0; j < 2; ++j) acc[i][j] = f32x4{0.f, 0.f, 0.f, 0.f};

  for (int k0 = 0; k0 < C_; k0 += 32) {
    gl_lds16(ag + k0, al);
    gl_lds16(bg0 + k0, bl0);
    gl_lds16(bg1 + k0, bl1);
    __syncthreads();
    bf16x8 af[4], bf[2];
#pragma unroll
    for (int ms = 0; ms < 4; ++ms)
      af[ms] = *reinterpret_cast<const bf16x8*>(As + (ms * 16 + n) * 32 + kg * 8);
#pragma unroll
    for (int ns = 0; ns < 2; ++ns)
      bf[ns] = *reinterpret_cast<const bf16x8*>(Bs + (w * 32 + ns * 16 + n) * 32 + kg * 8);
#pragma unroll
    for (int ms = 0; ms < 4; ++ms)
#pragma unroll
      for (int ns = 0; ns < 2; ++ns)
        acc[ms][ns] = __builtin_amdgcn_mfma_f32_16x16x32_bf16(af[ms], bf[ns], acc[ms][ns], 0, 0, 0);
    __syncthreads();
  }

#pragma unroll
  for (int ms = 0; ms < 4; ++ms) {
#pragma unroll
    for (int r = 0; r < 4; ++r) {
      const int row = m0 + ms * 16 + kg * 4 + r;
      float* cp = Cout + (size_t)row * C_ + n0 + w * 32 + n;
#pragma unroll
      for (int ns = 0; ns < 2; ++ns) cp[ns * 16] = acc[ms][ns][r];
    }
  }
}

// ---------------------------------------------------------------------------
// EMA pass 1: per-(bh,chunk) local scan (zero initial state).
// ---------------------------------------------------------------------------
__global__ __launch_bounds__(256) void ema_local_kernel(const float* __restrict__ xl,
                                                        float* __restrict__ loc,
                                                        float* __restrict__ carr,
                                                        const float* __restrict__ la_coef) {
  const int c = blockIdx.x % SCN_;
  const int bh = blockIdx.x / SCN_;
  const int b = bh / NH_, h = bh % NH_;
  const int tid = threadIdx.x;
  const int t0 = c * SCL_;
  __shared__ float buf[SCL_ * HS_];  // 32 KB

  const float alpha = la_coef[h];
  const float onema = 1.0f - alpha;
  const float4* src4 = reinterpret_cast<const float4*>(xl + (size_t)b * T_ * C_ + h * HS_);

  float4* buf4 = reinterpret_cast<float4*>(buf);
#pragma unroll
  for (int i = 0; i < (SCL_ * HS_ / 4) / 256; ++i) {  // 8 iters
    const int idx = tid + i * 256;
    const int tt = idx >> 4, d4 = idx & 15;
    buf4[tt * 16 + d4] = src4[(size_t)(t0 + tt) * (C_ / 4) + d4];
  }
  __syncthreads();
  if (tid < 64) {
    const int d = tid;
    float c2 = 0.0f;
#pragma unroll 8
    for (int tt = 0; tt < SCL_; ++tt) {
      c2 = alpha * c2 + onema * buf[tt * HS_ + d];
      buf[tt * HS_ + d] = c2;
    }
    carr[(size_t)(bh * SCN_ + c) * HS_ + d] = c2;  // chunk-final
  }
  __syncthreads();
  float4* dst4 = reinterpret_cast<float4*>(loc + ((size_t)bh * T_ + t0) * HS_);
#pragma unroll
  for (int i = 0; i < (SCL_ * HS_ / 4) / 256; ++i) dst4[tid + i * 256] = buf4[tid + i * 256];
}

// ---------------------------------------------------------------------------
// EMA pass 2 (fused carry): combine chunk-finals (Horner), row-normalize,
// kb-scale, emit bf16 k in TILE-SLOT layout (BH, NT, g=hs>>3, key, 8).
// ---------------------------------------------------------------------------
__global__ __launch_bounds__(256) void ema_fix_norm_kernel(const float* __restrict__ loc,
                                                           const float* __restrict__ carr,
                                                           __hip_bfloat16* __restrict__ kb16,
                                                           const float* __restrict__ la_coef,
                                                           const float* __restrict__ kernel_beta) {
  const int c = blockIdx.x % SCN_;
  const int bh = blockIdx.x / SCN_;
  const int h = bh % NH_;
  const int w = threadIdx.x >> 6, l = threadIdx.x & 63;

  const float alpha = la_coef[h];
  const float aL = __powf(alpha, (float)SCL_);
  const float kbs = expf(fminf(kernel_beta[h] * 10.0f, 5.0f));

  float A = 0.0f;
  for (int cc = 0; cc < c; ++cc) A = aL * A + carr[(size_t)(bh * SCN_ + cc) * HS_ + l];

  const float* lp = loc + ((size_t)bh * T_ + c * SCL_ + w * 32) * HS_ + l;
  __hip_bfloat16* kt = kb16 + (size_t)bh * NT_ * TEL_;
  const int g = l >> 3, j = l & 7;

  float s = __powf(alpha, (float)(w * 32 + 1));
  for (int rr = 0; rr < 32; ++rr) {
    const int t = c * SCL_ + w * 32 + rr;
    float val = lp[rr * HS_] + s * A;
    float ss = val * val;
#pragma unroll
    for (int m = 32; m; m >>= 1) ss += __shfl_xor(ss, m);
    const int tile = t >> 6, key = t & 63;
    kt[(size_t)tile * TEL_ + (g * 64 + key) * 8 + j] = __float2bfloat16(val * (kbs / sqrtf(ss)));
    s *= alpha;
  }
}

// ---------------------------------------------------------------------------
// Build v, emit TILE-SLOT bf16 vt (BH, NT, kk=key>>3, hs, 8).
// ---------------------------------------------------------------------------
__global__ __launch_bounds__(256) void vprep_kernel(const float* __restrict__ xv,
                                                    __hip_bfloat16* __restrict__ vt,
                                                    const float* __restrict__ value_beta,
                                                    const float* __restrict__ v_coef) {
  const int tc = blockIdx.x % NT_;
  const int bh = blockIdx.x / NT_;
  const int h = bh % NH_, b = bh / NH_;
  const int t0 = tc * 64;
  const int w = threadIdx.x >> 6, l = threadIdx.x & 63;
  __shared__ __hip_bfloat16 tile[64][66];

  const float c = v_coef[h];
  const float vb = expf(value_beta[h] * 10.0f);

  for (int r = 0; r < 16; ++r) {
    const int tl = w * 16 + r;
    const int t = t0 + tl;
    const float* base = xv + ((size_t)b * T_ + t) * C_ + h * HS_ + l;
    const float cur = base[0];
    const float nxt = (t + 1 < T_) ? base[C_] : 0.0f;
    float val = nxt * (1.0f - c) + cur * c;
    float ssum = val * val;
#pragma unroll
    for (int m = 32; m; m >>= 1) ssum += __shfl_xor(ssum, m);
    tile[tl][l] = __float2bfloat16(val * (vb / sqrtf(ssum)));
  }
  __syncthreads();
  __hip_bfloat16* vtb = vt + (size_t)(bh * NT_ + tc) * TEL_;
  const int kk = l >> 3, j = l & 7;  // l = key
  for (int rr = 0; rr < 16; ++rr) {
    const int hs = w * 16 + rr;
    vtb[(kk * 64 + hs) * 8 + j] = tile[l][hs];
  }
}

// ---------------------------------------------------------------------------
// MFMA flash attention: 64 queries/block, single-tile staging (24.7 KB LDS),
// slot layout (0 conflicts), XCD-LOCALITY SWIZZLE: all 32 blocks of a bh land
// on XCD bh%8 (consecutive-id round-robin) -> per-XCD working set 2 MB < 4 MB
// L2 -> staging DMAs hit L2. 1024 blocks = 4/CU. No online max (|s| <= e^2).
// ---------------------------------------------------------------------------
__global__ __launch_bounds__(256) void attn_mfma_kernel(
    const __hip_bfloat16* __restrict__ kb,   // (BH, NT, g, key, 8) slot tiles
    const __hip_bfloat16* __restrict__ vt,   // (BH, NT, kk, hs, 8) slot tiles
    __hip_bfloat16* __restrict__ y) {        // (B, T, C) bf16
  __shared__ __hip_bfloat16 Ks[TEL_];
  __shared__ __hip_bfloat16 Vs[TEL_];
  __shared__ __hip_bfloat16 Ps[4][16 * 68];  // per-wave P, pad 68 (conflict-free)

  // swizzle: id -> (xcd, bh, qt): bh % 8 == xcd == id % 8; longest-qt first.
  const int id = (int)blockIdx.x;
  const int xcd = id & 7;
  const int s = id >> 3;                 // 0..127
  const int bh = xcd + 8 * (s & 3);      // 32 bh, grouped 4 per XCD
  const int qt = (NT_ - 1) - (s >> 2);   // 31..0, heavy blocks first
  const int b = bh / NH_, h = bh % NH_;
  const int q0 = qt * 64;
  const int w = threadIdx.x >> 6;
  const int l = threadIdx.x & 63;
  const int n = l & 15;
  const int kg = l >> 4;
  const int qq = w * 16 + n;             // within-tile query index
  const int query = q0 + qq;
  const int lo = l * 8;                  // per-lane 16B offset (elements)
  const int tb = bh * NT_;

  // Q B-fragments from global slot tile (once)
  bf16x8 qf0, qf1;
  {
    const __hip_bfloat16* qtile = kb + (size_t)(tb + qt) * TEL_;
    qf0 = *reinterpret_cast<const bf16x8*>(qtile + (kg * 64 + qq) * 8);
    qf1 = *reinterpret_cast<const bf16x8*>(qtile + ((kg + 4) * 64 + qq) * 8);
  }

  f32x4 accO[4];
#pragma unroll
  for (int i = 0; i < 4; ++i) accO[i] = f32x4{0.f, 0.f, 0.f, 0.f};
  float l_acc = 0.0f;

  __hip_bfloat16* Pw = Ps[w];
  int* Pwi = reinterpret_cast<int*>(Pw);

  for (int jt = 0; jt <= qt; ++jt) {
    __syncthreads();  // previous compute done -> safe to overwrite tiles
    {
      const size_t tg = (size_t)(tb + jt) * TEL_;
      gl_lds16(kb + tg + w * 1024 + lo, &Ks[w * 1024 + lo]);
      gl_lds16(kb + tg + w * 1024 + 512 + lo, &Ks[w * 1024 + 512 + lo]);
      gl_lds16(vt + tg + w * 1024 + lo, &Vs[w * 1024 + lo]);
      gl_lds16(vt + tg + w * 1024 + 512 + lo, &Vs[w * 1024 + 512 + lo]);
    }
    __syncthreads();  // DMA drained

    const bool diag = (jt == qt);

    // ---- S^T = K @ Q^T (slot reads, 2-way max bank aliasing) ----
    f32x4 accS[4];
#pragma unroll
    for (int ms = 0; ms < 4; ++ms) {
      bf16x8 a0 = *reinterpret_cast<const bf16x8*>(Ks + (kg * 64 + ms * 16 + n) * 8);
      bf16x8 a1 = *reinterpret_cast<const bf16x8*>(Ks + ((kg + 4) * 64 + ms * 16 + n) * 8);
      f32x4 z{0.f, 0.f, 0.f, 0.f};
      z = __builtin_amdgcn_mfma_f32_16x16x32_bf16(a0, qf0, z, 0, 0, 0);
      accS[ms] = __builtin_amdgcn_mfma_f32_16x16x32_bf16(a1, qf1, z, 0, 0, 0);
    }

    // ---- exp + causal mask + row-sum; P to wave-local LDS ----
    float lsum = 0.0f;
#pragma unroll
    for (int ms = 0; ms < 4; ++ms) {
      const int kbase = ms * 16 + kg * 4;
      float p[4];
#pragma unroll
      for (int r = 0; r < 4; ++r) {
        const float e = __expf(accS[ms][r]);
        p[r] = (!diag || (kbase + r < qq)) ? e : 0.0f;
        lsum += p[r];
      }
      const int po = n * 34 + ms * 8 + kg * 2;
      Pwi[po] = pack_bf16(p[0], p[1]);
      Pwi[po + 1] = pack_bf16(p[2], p[3]);
    }
    lsum += __shfl_xor(lsum, 16);
    lsum += __shfl_xor(lsum, 32);
    l_acc += lsum;

    // ---- O^T += V^T @ P^T ----
#pragma unroll
    for (int ks = 0; ks < 2; ++ks) {
      union { ushort4 u[2]; bf16x8 v; } pr;
      const __hip_bfloat16* pp = Pw + n * 68 + ks * 32 + kg * 8;
      pr.u[0] = *reinterpret_cast<const ushort4*>(pp);
      pr.u[1] = *reinterpret_cast<const ushort4*>(pp + 4);
#pragma unroll
      for (int mo = 0; mo < 4; ++mo) {
        bf16x8 av = *reinterpret_cast<const bf16x8*>(Vs + ((ks * 4 + kg) * 64 + mo * 16 + n) * 8);
        accO[mo] = __builtin_amdgcn_mfma_f32_16x16x32_bf16(av, pr.v, accO[mo], 0, 0, 0);
      }
    }
  }

  // ---- epilogue ----
  const float inv = (query == 0) ? 0.0f : 1.0f / l_acc;
  __hip_bfloat16* yb = y + ((size_t)b * T_ + query) * C_ + h * HS_;
#pragma unroll
  for (int mo = 0; mo < 4; ++mo) {
    int2 pkd;
    pkd.x = pack_bf16(accO[mo][0] * inv, accO[mo][1] * inv);
    pkd.y = pack_bf16(accO[mo][2] * inv, accO[mo][3] * inv);
    *reinterpret_cast<int2*>(yb + mo * 16 + kg * 4) = pkd;
  }
}

// ---------------------------------------------------------------------------
extern "C" void kernel_launch(void* const* d_in, const int* in_sizes, int n_in,
                              void* d_out, int out_size, void* d_ws, size_t ws_size,
                              hipStream_t stream) {
  const float* x           = (const float*)d_in[0];
  const float* W_la        = (const float*)d_in[1];
  const float* la_coef     = (const float*)d_in[2];
  const float* kernel_beta = (const float*)d_in[3];
  const float* value_beta  = (const float*)d_in[4];
  const float* W_v         = (const float*)d_in[5];
  const float* v_coef      = (const float*)d_in[6];
  const float* W_proj      = (const float*)d_in[7];
  float* out = (float*)d_out;

  char* wsb = (char*)d_ws;
  const size_t MB = 1024u * 1024u;
  __hip_bfloat16* x16    = (__hip_bfloat16*)(wsb);            // 8 MB
  __hip_bfloat16* Wcat   = (__hip_bfloat16*)(wsb + 8 * MB);   // 4 MB (W_laT | W_vT)
  __hip_bfloat16* WprojT = (__hip_bfloat16*)(wsb + 12 * MB);  // 2 MB
  float* carr            = (float*)(wsb + 14 * MB);           // 128 KB
  float* xl              = (float*)(wsb + 16 * MB);           // 16 MB
  float* xv              = (float*)(wsb + 32 * MB);           // 16 MB
  __hip_bfloat16* kb16   = (__hip_bfloat16*)(wsb + 48 * MB);  // 8 MB
  __hip_bfloat16* vt16   = (__hip_bfloat16*)(wsb + 56 * MB);  // 8 MB
  float* loc             = xv;                                 // reuse: xv dead after vprep
  __hip_bfloat16* y16    = (__hip_bfloat16*)(wsb + 16 * MB);  // aliases xl (dead after pass1)
  (void)ws_size; (void)in_sizes; (void)n_in; (void)out_size;

  const int M = B_ * T_;

  cvt_bf16_kernel<<<dim3((M * C_) / 2048), dim3(256), 0, stream>>>(x, x16);
  cvtT_all_kernel<<<dim3(C_ / 64, C_ / 64, 3), dim3(256), 0, stream>>>(W_la, W_v, W_proj, Wcat, WprojT);

  gemm_in_kernel<<<dim3(2 * C_ / 128, M / 128), dim3(256), 0, stream>>>(x16, Wcat, xl, xv);
  vprep_kernel<<<dim3(B_ * NH_ * NT_), dim3(256), 0, stream>>>(xv, vt16, value_beta, v_coef);
  ema_local_kernel<<<dim3(B_ * NH_ * SCN_), dim3(256), 0, stream>>>(xl, loc, carr, la_coef);
  ema_fix_norm_kernel<<<dim3(B_ * NH_ * SCN_), dim3(256), 0, stream>>>(loc, carr, kb16, la_coef, kernel_beta);
  attn_mfma_kernel<<<dim3(8 * 128), dim3(256), 0, stream>>>(kb16, vt16, y16);
  gemm_proj_kernel<<<dim3(C_ / 128, M / 64), dim3(256), 0, stream>>>(y16, WprojT, out);
}